// Round 4
// baseline (144.615 us; speedup 1.0000x reference)
//
#include <hip/hip_runtime.h>

#define NEGV -1000000000.0f

// Native vector type (HIP's float4 is a struct; nontemporal builtins
// require a scalar/native-vector pointee).
typedef float f32x4 __attribute__((ext_vector_type(4)));

// x: [B, S, S] fp32, S = 4096. mask = (row < n-1) && (col > row) -> NEGV.
// One 256-thread block per ROW PAIR (r, S-1-r) of one matrix: every block
// does ~1024 loads + 2048 stores, so work and read/write mix are uniform
// across the dispatch (no write-only vs copy-only phases, no heavy tail).
__global__ __launch_bounds__(256) void submask_pair_kernel(
    const f32x4* __restrict__ x4,
    f32x4* __restrict__ o4,
    const int* __restrict__ n_ptr)
{
    const int n = *n_ptr;                     // uniform scalar
    const int b = blockIdx.x >> 11;           // matrix index (2048 pairs each)
    const int i = blockIdx.x & 2047;          // pair index
    const int row0 = i;                       // top row of the pair
    const int row1 = 4095 - i;                // bottom row of the pair
    const f32x4 NEG4 = {NEGV, NEGV, NEGV, NEGV};
    const int t = threadIdx.x;

#pragma unroll
    for (int half = 0; half < 2; ++half) {
        const int row = half ? row1 : row0;
        const bool full = (row >= n - 1);              // untouched row
        const int nload = full ? 1024 : ((row >> 2) + 1);
        const int sv    = full ? -1   : (row >> 2);    // straddle vec
        const int rm    = row & 3;
        const size_t base = (((size_t)b << 12) | (size_t)row) << 10;

#pragma unroll
        for (int k = 0; k < 4; ++k) {
            const int v = t + (k << 8);
            if (v < nload) {
                f32x4 d = __builtin_nontemporal_load(&x4[base + v]);
                if (v == sv) {
                    if (rm < 1) d.y = NEGV;
                    if (rm < 2) d.z = NEGV;
                    if (rm < 3) d.w = NEGV;
                }
                __builtin_nontemporal_store(d, &o4[base + v]);
            } else {
                __builtin_nontemporal_store(NEG4, &o4[base + v]);
            }
        }
    }
}

extern "C" void kernel_launch(void* const* d_in, const int* in_sizes, int n_in,
                              void* d_out, int out_size, void* d_ws, size_t ws_size,
                              hipStream_t stream) {
    const float* x = (const float*)d_in[0];
    const int* n_ptr = (const int*)d_in[1];
    float* out = (float*)d_out;

    const int total = in_sizes[0];            // B * S * S = 134217728
    const int pairs = total >> 13;            // B * S/2 = 16384 row pairs

    submask_pair_kernel<<<pairs, 256, 0, stream>>>(
        (const f32x4*)x, (f32x4*)out, n_ptr);
}